// Round 1
// baseline (664.851 us; speedup 1.0000x reference)
//
#include <hip/hip_runtime.h>
#include <cstddef>

// MediumLSTM: 3-layer LSTM (D=128 -> H1=32 -> H2=16 -> H3=8), T=64, B=8192, FC -> 1.
// Fused persistent kernel: 512 blocks x 256 threads, 16 batch rows/block.
// f16 MFMA (16x16x32) for all gate GEMMs, fp32 state + nonlinearities.
//
// LDS layout per block (62080 B total, fits 64KB static; 2 blocks/CU):
//   xh   [16][200] f16 : per-batch-row concat vector
//        [0:128)=x_t  [128:160)=h1  [160:176)=h2  [176:184)=h3  [184:200)=0/pad
//   wcat1[128][168] f16: permuted layer-1 gate rows, cols [0:128)=w_ih1 [128:160)=w_hh1
//   wcat2[ 64][ 72] f16: permuted layer-2 rows, [0:32)=w_ih2 [32:48)=w_hh2 [48:64)=0
//   wcat3[ 32][ 40] f16: permuted layer-3 rows, [0:16)=w_ih3 [16:24)=w_hh3 [24:32)=0
//   bcat [224]      f32: b_ih+b_hh per layer (original gate order)
// Row strides (200,168,72,40 f16 = 100,84,36,20 words) are == 4 mod 32 words ->
// b128 fragment loads spread over 8 bank groups -> data-path-bound (8 cy), no conflicts.
//
// Gate permutation: wave w's MFMA N-tiles hold complete i,f,g,o for its hidden
// units, so the LSTM cell update is done with intra-quad __shfl (no preact LDS).
// c-state is thread-private (lane->unit mapping is identical every timestep).

typedef _Float16 h8_t __attribute__((ext_vector_type(8)));
typedef _Float16 h4_t __attribute__((ext_vector_type(4)));
typedef float    f4_t __attribute__((ext_vector_type(4)));

#define B_TOT   8192
#define T_LEN   64
#define D_IN    128
#define MB      16          // batch rows per block

#define XH_S    200         // xh row stride (f16)
#define W1_S    168
#define W2_S    72
#define W3_S    40

__device__ __forceinline__ float sig_(float x) {
    return 1.0f / (1.0f + __expf(-x));
}
__device__ __forceinline__ float tanh_(float x) {
    // stable: +inf -> 1, -inf -> -1
    float e = __expf(2.0f * x);
    return 1.0f - 2.0f / (e + 1.0f);
}

__global__ __launch_bounds__(256, 2)
void lstm_fused(const float* __restrict__ x,
                const float* __restrict__ w_ih1, const float* __restrict__ w_hh1,
                const float* __restrict__ b_ih1, const float* __restrict__ b_hh1,
                const float* __restrict__ w_ih2, const float* __restrict__ w_hh2,
                const float* __restrict__ b_ih2, const float* __restrict__ b_hh2,
                const float* __restrict__ w_ih3, const float* __restrict__ w_hh3,
                const float* __restrict__ b_ih3, const float* __restrict__ b_hh3,
                const float* __restrict__ fc_w, const float* __restrict__ fc_b,
                float* __restrict__ out)
{
    __shared__ __align__(16) _Float16 xh[MB * XH_S];
    __shared__ __align__(16) _Float16 wcat1[128 * W1_S];
    __shared__ __align__(16) _Float16 wcat2[64 * W2_S];
    __shared__ __align__(16) _Float16 wcat3[32 * W3_S];
    __shared__ float bcat[224];

    const int tid  = threadIdx.x;
    const int lane = tid & 63;
    const int wv   = tid >> 6;      // wave 0..3
    const int nl   = lane & 15;     // MFMA n-lane / m-lane
    const int qd   = lane >> 4;     // quad 0..3

    // ---- zero all LDS (covers all pad + zero-weight regions) ----
    for (int i = tid; i < MB * XH_S;   i += 256) xh[i]    = (_Float16)0.f;
    for (int i = tid; i < 128 * W1_S;  i += 256) wcat1[i] = (_Float16)0.f;
    for (int i = tid; i < 64 * W2_S;   i += 256) wcat2[i] = (_Float16)0.f;
    for (int i = tid; i < 32 * W3_S;   i += 256) wcat3[i] = (_Float16)0.f;
    __syncthreads();

    // ---- stage weights (f16, gate-permuted row order) ----
    // L1: permuted row g' = 32*w + s  ->  original gate G = 8*w + (s&7) + 32*(s>>3)
    for (int idx = tid; idx < 128 * 160; idx += 256) {
        int gp = idx / 160, k = idx - gp * 160;
        int w = gp >> 5, s = gp & 31;
        int G = 8 * w + (s & 7) + 32 * (s >> 3);
        float v = (k < 128) ? w_ih1[G * 128 + k] : w_hh1[G * 32 + (k - 128)];
        wcat1[gp * W1_S + k] = (_Float16)v;
    }
    // L2: g' = 16*w + s -> G = 4*w + (s&3) + 16*(s>>2)
    for (int idx = tid; idx < 64 * 48; idx += 256) {
        int gp = idx / 48, k = idx - gp * 48;
        int w = gp >> 4, s = gp & 15;
        int G = 4 * w + (s & 3) + 16 * (s >> 2);
        float v = (k < 32) ? w_ih2[G * 32 + k] : w_hh2[G * 16 + (k - 32)];
        wcat2[gp * W2_S + k] = (_Float16)v;
    }
    // L3: g' = 16*w + s (w<2) -> G = 4*w + (s&3) + 8*(s>>2)
    for (int idx = tid; idx < 32 * 24; idx += 256) {
        int gp = idx / 24, k = idx - gp * 24;
        int w = gp >> 4, s = gp & 15;
        int G = 4 * w + (s & 3) + 8 * (s >> 2);
        float v = (k < 16) ? w_ih3[G * 16 + k] : w_hh3[G * 8 + (k - 16)];
        wcat3[gp * W3_S + k] = (_Float16)v;
    }
    for (int j = tid; j < 224; j += 256) {
        float v;
        if (j < 128)       v = b_ih1[j] + b_hh1[j];
        else if (j < 192)  v = b_ih2[j - 128] + b_hh2[j - 128];
        else               v = b_ih3[j - 192] + b_hh3[j - 192];
        bcat[j] = v;
    }

    // thread-private cell state (mapping lane->unit is timestep-invariant)
    float c1s[4] = {0.f, 0.f, 0.f, 0.f};
    float c2s[4] = {0.f, 0.f, 0.f, 0.f};
    float c3s[4] = {0.f, 0.f, 0.f, 0.f};

    const int b0  = blockIdx.x * MB;
    const int xc  = tid & 31;    // x-stage column (float4 index)
    const int xr  = tid >> 5;    // x-stage row base (0..7)

    // shfl source lanes (stay within 16-lane quad-group)
    const int sh4  = (lane & 48) | ((lane + 4)  & 15);
    const int sh8  = (lane & 48) | ((lane + 8)  & 15);
    const int sh12 = (lane & 48) | ((lane + 12) & 15);

    __syncthreads();

    for (int t = 0; t < T_LEN; ++t) {
        // ---------- Phase A: stage x_t (coalesced float4, convert f16) ----------
        #pragma unroll
        for (int ri = 0; ri < 2; ++ri) {
            int row = xr + 8 * ri;
            const float4 v = *(const float4*)(x + ((size_t)(b0 + row) * T_LEN + t) * D_IN + xc * 4);
            h4_t hv = { (_Float16)v.x, (_Float16)v.y, (_Float16)v.z, (_Float16)v.w };
            *(h4_t*)(&xh[row * XH_S + xc * 4]) = hv;
        }
        __syncthreads();   // bar_A

        // ---------- Phase B1: layer-1 gates, K=160 over [x|h1] ----------
        f4_t acc0 = {0.f, 0.f, 0.f, 0.f};
        f4_t acc1 = {0.f, 0.f, 0.f, 0.f};
        {
            const _Float16* arow  = &xh[nl * XH_S];
            const _Float16* brow0 = &wcat1[(32 * wv + nl) * W1_S];
            const _Float16* brow1 = &wcat1[(32 * wv + 16 + nl) * W1_S];
            #pragma unroll
            for (int kc = 0; kc < 5; ++kc) {
                int ko = kc * 32 + qd * 8;
                h8_t a  = *(const h8_t*)(arow + ko);
                h8_t b0f = *(const h8_t*)(brow0 + ko);
                h8_t b1f = *(const h8_t*)(brow1 + ko);
                acc0 = __builtin_amdgcn_mfma_f32_16x16x32_f16(a, b0f, acc0, 0, 0, 0);
                acc1 = __builtin_amdgcn_mfma_f32_16x16x32_f16(a, b1f, acc1, 0, 0, 0);
            }
        }
        __syncthreads();   // bar_B1: all x/h1 reads done before h1 rewritten

        // ---------- Phase C1: update layer-1 state, units [8wv, 8wv+8) ----------
        #pragma unroll
        for (int r = 0; r < 4; ++r) {
            float fsh = __shfl(acc0[r], sh8, 64);
            float osh = __shfl(acc1[r], sh8, 64);
            if (nl < 8) {
                int u = 8 * wv + nl;
                int m = 4 * qd + r;
                float pi = acc0[r] + bcat[u];
                float pf = fsh     + bcat[u + 32];
                float pg = acc1[r] + bcat[u + 64];
                float po = osh     + bcat[u + 96];
                float ig = sig_(pi), fg = sig_(pf);
                float gg = tanh_(pg), og = sig_(po);
                float c  = fg * c1s[r] + ig * gg;
                c1s[r] = c;
                float h  = og * tanh_(c);
                xh[m * XH_S + 128 + u] = (_Float16)h;
            }
        }
        __syncthreads();   // bar_C1

        // ---------- Phase B2: layer-2 gates, K=64 over [h1|h2|0] ----------
        f4_t acc2 = {0.f, 0.f, 0.f, 0.f};
        {
            const _Float16* arow = &xh[nl * XH_S + 128];
            const _Float16* brow = &wcat2[(16 * wv + nl) * W2_S];
            #pragma unroll
            for (int kc = 0; kc < 2; ++kc) {
                int ko = kc * 32 + qd * 8;
                h8_t a  = *(const h8_t*)(arow + ko);
                h8_t bf = *(const h8_t*)(brow + ko);
                acc2 = __builtin_amdgcn_mfma_f32_16x16x32_f16(a, bf, acc2, 0, 0, 0);
            }
        }
        __syncthreads();   // bar_B2: h1/h2 reads done before h2 rewritten

        // ---------- Phase C2: update layer-2 state, units [4wv, 4wv+4) ----------
        #pragma unroll
        for (int r = 0; r < 4; ++r) {
            float fsh = __shfl(acc2[r], sh4, 64);
            float gsh = __shfl(acc2[r], sh8, 64);
            float osh = __shfl(acc2[r], sh12, 64);
            if (nl < 4) {
                int u = 4 * wv + nl;
                int m = 4 * qd + r;
                float pi = acc2[r] + bcat[128 + u];
                float pf = fsh     + bcat[128 + u + 16];
                float pg = gsh     + bcat[128 + u + 32];
                float po = osh     + bcat[128 + u + 48];
                float ig = sig_(pi), fg = sig_(pf);
                float gg = tanh_(pg), og = sig_(po);
                float c  = fg * c2s[r] + ig * gg;
                c2s[r] = c;
                float h  = og * tanh_(c);
                xh[m * XH_S + 160 + u] = (_Float16)h;
            }
        }
        __syncthreads();   // bar_C2

        // ---------- Phase B3: layer-3 gates, K=32 over [h2|h3|0] (waves 0,1) ----------
        f4_t acc3 = {0.f, 0.f, 0.f, 0.f};
        if (wv < 2) {
            const _Float16* arow = &xh[nl * XH_S + 160];
            const _Float16* brow = &wcat3[(16 * wv + nl) * W3_S];
            h8_t a  = *(const h8_t*)(arow + qd * 8);
            h8_t bf = *(const h8_t*)(brow + qd * 8);
            acc3 = __builtin_amdgcn_mfma_f32_16x16x32_f16(a, bf, acc3, 0, 0, 0);
        }
        __syncthreads();   // bar_B3: h2/h3 reads done before h3 rewritten

        // ---------- Phase C3: update layer-3 state, units [4wv, 4wv+4) (waves 0,1) ----------
        #pragma unroll
        for (int r = 0; r < 4; ++r) {
            float fsh = __shfl(acc3[r], sh4, 64);
            float gsh = __shfl(acc3[r], sh8, 64);
            float osh = __shfl(acc3[r], sh12, 64);
            if (wv < 2 && nl < 4) {
                int u = 4 * wv + nl;
                int m = 4 * qd + r;
                float pi = acc3[r] + bcat[192 + u];
                float pf = fsh     + bcat[192 + u + 8];
                float pg = gsh     + bcat[192 + u + 16];
                float po = osh     + bcat[192 + u + 24];
                float ig = sig_(pi), fg = sig_(pf);
                float gg = tanh_(pg), og = sig_(po);
                float c  = fg * c3s[r] + ig * gg;
                c3s[r] = c;
                float h  = og * tanh_(c);
                xh[m * XH_S + 176 + u] = (_Float16)h;
            }
        }
        // no barrier: next Phase A writes x-region only (disjoint from h3);
        // all h3 readers are beyond bar_A/bar_B1 of the next iteration.
    }
    __syncthreads();   // make final h3 visible

    // ---------- FC head: out[b] = fc_w . h3[b] + fc_b ----------
    if (tid < MB) {
        float acc = fc_b[0];
        #pragma unroll
        for (int u = 0; u < 8; ++u)
            acc += fc_w[u] * (float)xh[tid * XH_S + 176 + u];
        out[b0 + tid] = acc;
    }
}

extern "C" void kernel_launch(void* const* d_in, const int* in_sizes, int n_in,
                              void* d_out, int out_size, void* d_ws, size_t ws_size,
                              hipStream_t stream) {
    (void)in_sizes; (void)n_in; (void)d_ws; (void)ws_size; (void)out_size;
    const float* x     = (const float*)d_in[0];
    const float* w_ih1 = (const float*)d_in[1];
    const float* w_hh1 = (const float*)d_in[2];
    const float* b_ih1 = (const float*)d_in[3];
    const float* b_hh1 = (const float*)d_in[4];
    const float* w_ih2 = (const float*)d_in[5];
    const float* w_hh2 = (const float*)d_in[6];
    const float* b_ih2 = (const float*)d_in[7];
    const float* b_hh2 = (const float*)d_in[8];
    const float* w_ih3 = (const float*)d_in[9];
    const float* w_hh3 = (const float*)d_in[10];
    const float* b_ih3 = (const float*)d_in[11];
    const float* b_hh3 = (const float*)d_in[12];
    const float* fc_w  = (const float*)d_in[13];
    const float* fc_b  = (const float*)d_in[14];

    dim3 grid(B_TOT / MB);   // 512 blocks
    dim3 block(256);
    hipLaunchKernelGGL(lstm_fused, grid, block, 0, stream,
                       x, w_ih1, w_hh1, b_ih1, b_hh1,
                       w_ih2, w_hh2, b_ih2, b_hh2,
                       w_ih3, w_hh3, b_ih3, b_hh3,
                       fc_w, fc_b, (float*)d_out);
}